// Round 1
// baseline (520.253 us; speedup 1.0000x reference)
//
#include <hip/hip_runtime.h>
#include <hip/hip_bf16.h>
#include <math.h>
#include <stdint.h>

// TGN attention node, algebraically restructured:
//   scores[b,h,s] = gene[b,s,:] . qk[b,h,:],  qk = C . source[b] + cb
//     C[h*512+j, m] = (1/16) * sum_{i in head h} Wk[i,j] * Wq[i,m]
//     cb[h*512+j]   = (1/16) * sum_{i in head h} Wk[i,j] * bq[i]
//   (q.bk term is constant over s -> cancels in softmax; bk unused)
//   gbar[b,h,:] = sum_s w[b,h,s] * gene[b,s,:]      (sum_s w = 1 absorbs bv)
//   out = ( [gbar_h0|gbar_h1] @ D^T + e ) * gate + source
//     D[n, h*512+j] = sum_{i in head h} Wout[n,i] * Wv[i,j],  e = Wout.bv + bout
//     gate[b] = invalid[b] ? 0 : mask_n[b]
// K/V projections (137 of 142 GFLOP) are never materialized.

#define NB 4096
#define SNB 32
#define DM 512

typedef __attribute__((ext_vector_type(8))) short bf16x8;
typedef __attribute__((ext_vector_type(4))) float f32x4;

__device__ __forceinline__ unsigned short f2bf(float f) {
    union { float f; unsigned int u; } v; v.f = f;
    unsigned int u = v.u;
    return (unsigned short)((u + 0x7FFFu + ((u >> 16) & 1u)) >> 16);
}
__device__ __forceinline__ float bf2f(unsigned short s) {
    union { unsigned int u; float f; } v; v.u = ((unsigned int)s) << 16;
    return v.f;
}

// ---------------- mask dtype detector (bool could arrive as u8 / i32 / f32) --
__global__ void k_detect(const unsigned int* __restrict__ m, int* __restrict__ mode) {
    __shared__ int fF, fH;
    if (threadIdx.x == 0) { fF = 0; fH = 0; }
    __syncthreads();
    int lf = 0, lh = 0;
    // 32768 words is in-bounds under all three interpretations (u8: exactly B*S bytes)
    for (int i = threadIdx.x; i < 32768; i += blockDim.x) {
        unsigned int w = m[i];
        lf |= (w == 0x3F800000u);
        lh |= ((w & 0xFFFFFF00u) != 0u);
    }
    if (lf) atomicOr(&fF, 1);
    if (lh) atomicOr(&fH, 1);
    __syncthreads();
    if (threadIdx.x == 0) *mode = fF ? 2 : (fH ? 1 : 0);
}

// ---------------- source fp32 -> bf16 ---------------------------------------
__global__ void k_conv_src(const float* __restrict__ s, unsigned short* __restrict__ d) {
    int i = blockIdx.x * 256 + threadIdx.x;          // over float4 groups
    float4 v = ((const float4*)s)[i];
    ushort4 o;
    o.x = f2bf(v.x); o.y = f2bf(v.y); o.z = f2bf(v.z); o.w = f2bf(v.w);
    ((ushort4*)d)[i] = o;
}

// ---------------- precompute C (scaled Wk^T Wq per head) and D (Wout Wv) ----
__global__ __launch_bounds__(256) void k_precomp_cd(
    const float* __restrict__ Wq, const float* __restrict__ Wk,
    const float* __restrict__ Wv, const float* __restrict__ Wout,
    unsigned short* __restrict__ C, unsigned short* __restrict__ D)
{
    __shared__ float Aa[32][33];
    __shared__ float Bb[32][33];
    int bid = blockIdx.x;
    int t = threadIdx.x;
    float acc0 = 0.f, acc1 = 0.f, acc2 = 0.f, acc3 = 0.f;

    if (bid < 512) {                       // C tile: head h, 32 j x 32 m
        int h = bid >> 8, rem = bid & 255;
        int j0 = (rem >> 4) << 5, m0 = (rem & 15) << 5;
        int ml = t & 31, jg = (t >> 5) << 2;
        for (int ic = 0; ic < 8; ic++) {
            int ib = h * 256 + ic * 32;
            for (int q = 0; q < 4; q++) {
                int idx = t + q * 256, rr = idx >> 5, cc = idx & 31;
                Aa[rr][cc] = Wk[(size_t)(ib + rr) * 512 + j0 + cc];   // [i][j]
                Bb[rr][cc] = Wq[(size_t)(ib + rr) * 512 + m0 + cc];   // [i][m]
            }
            __syncthreads();
            for (int i = 0; i < 32; i++) {
                float bqv = Bb[i][ml];
                acc0 += Aa[i][jg + 0] * bqv;
                acc1 += Aa[i][jg + 1] * bqv;
                acc2 += Aa[i][jg + 2] * bqv;
                acc3 += Aa[i][jg + 3] * bqv;
            }
            __syncthreads();
        }
        size_t p = (size_t)h * 512 + j0 + jg;
        C[(p + 0) * 512 + m0 + ml] = f2bf(0.0625f * acc0);
        C[(p + 1) * 512 + m0 + ml] = f2bf(0.0625f * acc1);
        C[(p + 2) * 512 + m0 + ml] = f2bf(0.0625f * acc2);
        C[(p + 3) * 512 + m0 + ml] = f2bf(0.0625f * acc3);
    } else {                               // D tile: head h, 32 n x 32 j
        int bid2 = bid - 512;
        int h = bid2 >> 8, rem = bid2 & 255;
        int n0 = (rem >> 4) << 5, j0 = (rem & 15) << 5;
        int jl = t & 31, ng = (t >> 5) << 2;
        for (int ic = 0; ic < 8; ic++) {
            int ib = h * 256 + ic * 32;
            for (int q = 0; q < 4; q++) {
                int idx = t + q * 256, rr = idx >> 5, cc = idx & 31;
                Aa[rr][cc] = Wout[(size_t)(n0 + rr) * 512 + ib + cc]; // [n][i]
                Bb[rr][cc] = Wv[(size_t)(ib + rr) * 512 + j0 + cc];   // [i][j]
            }
            __syncthreads();
            for (int i = 0; i < 32; i++) {
                float bvv = Bb[i][jl];
                acc0 += Aa[ng + 0][i] * bvv;
                acc1 += Aa[ng + 1][i] * bvv;
                acc2 += Aa[ng + 2][i] * bvv;
                acc3 += Aa[ng + 3][i] * bvv;
            }
            __syncthreads();
        }
        size_t col = (size_t)h * 512 + j0 + jl;
        D[(size_t)(n0 + ng + 0) * 1024 + col] = f2bf(acc0);
        D[(size_t)(n0 + ng + 1) * 1024 + col] = f2bf(acc1);
        D[(size_t)(n0 + ng + 2) * 1024 + col] = f2bf(acc2);
        D[(size_t)(n0 + ng + 3) * 1024 + col] = f2bf(acc3);
    }
}

// ---------------- cb and e vectors ------------------------------------------
__global__ void k_precomp_vec(const float* __restrict__ Wk, const float* __restrict__ bq,
                              const float* __restrict__ Wout, const float* __restrict__ bv,
                              const float* __restrict__ bout,
                              float* __restrict__ cb, float* __restrict__ e)
{
    int t = blockIdx.x * 256 + threadIdx.x;
    if (t < 1024) {
        int h = t >> 9, j = t & 511;
        float a = 0.f;
        for (int i = 0; i < 256; i++) a += Wk[(size_t)(h * 256 + i) * 512 + j] * bq[h * 256 + i];
        cb[t] = 0.0625f * a;
    } else if (t < 1536) {
        int n = t - 1024;
        float a = bout[n];
        for (int i = 0; i < 512; i++) a += Wout[(size_t)n * 512 + i] * bv[i];
        e[n] = a;
    }
}

// ---------------- MFMA GEMM, B^T layout: out[m,n] = sum_k A[m,k]*Bt[n,k] ----
// EPI 0: bf16 out = acc + bias[n]        (QK)
// EPI 1: f32 out  = (acc + bias[n]) * gscale[m] + resid[m,n]   (final)
template <int EPI>
__global__ __launch_bounds__(256) void k_gemm_bt(
    const unsigned short* __restrict__ A, const unsigned short* __restrict__ Bt,
    void* __restrict__ outp, const float* __restrict__ bias,
    const float* __restrict__ gscale, const float* __restrict__ resid,
    int M, int N, int K)
{
    __shared__ __align__(16) unsigned short As[64 * 40];  // pitch 40 kills 8-way conflicts
    __shared__ __align__(16) unsigned short Bs[64 * 40];
    int nt = N >> 6;
    int m0 = ((int)blockIdx.x / nt) << 6;
    int n0 = ((int)blockIdx.x % nt) << 6;
    int t = threadIdx.x;
    int w = t >> 6, l = t & 63;
    int wm = (w >> 1) << 5, wn = (w & 1) << 5;
    int quad = l >> 4, lm = l & 15;

    f32x4 acc00 = {0.f, 0.f, 0.f, 0.f}, acc01 = {0.f, 0.f, 0.f, 0.f};
    f32x4 acc10 = {0.f, 0.f, 0.f, 0.f}, acc11 = {0.f, 0.f, 0.f, 0.f};

    int srow = t >> 2, spart = t & 3;
    const unsigned short* ag = A + (size_t)(m0 + srow) * K + spart * 8;
    const unsigned short* bg = Bt + (size_t)(n0 + srow) * K + spart * 8;
    unsigned short* asl = As + srow * 40 + spart * 8;
    unsigned short* bsl = Bs + srow * 40 + spart * 8;

    for (int k0 = 0; k0 < K; k0 += 32) {
        *(bf16x8*)asl = *(const bf16x8*)ag;
        *(bf16x8*)bsl = *(const bf16x8*)bg;
        ag += 32; bg += 32;
        __syncthreads();
        bf16x8 a0 = *(const bf16x8*)(As + (wm + lm) * 40 + quad * 8);
        bf16x8 a1 = *(const bf16x8*)(As + (wm + 16 + lm) * 40 + quad * 8);
        bf16x8 b0 = *(const bf16x8*)(Bs + (wn + lm) * 40 + quad * 8);
        bf16x8 b1 = *(const bf16x8*)(Bs + (wn + 16 + lm) * 40 + quad * 8);
        acc00 = __builtin_amdgcn_mfma_f32_16x16x32_bf16(a0, b0, acc00, 0, 0, 0);
        acc01 = __builtin_amdgcn_mfma_f32_16x16x32_bf16(a0, b1, acc01, 0, 0, 0);
        acc10 = __builtin_amdgcn_mfma_f32_16x16x32_bf16(a1, b0, acc10, 0, 0, 0);
        acc11 = __builtin_amdgcn_mfma_f32_16x16x32_bf16(a1, b1, acc11, 0, 0, 0);
        __syncthreads();
    }
    f32x4 accs[2][2] = {{acc00, acc01}, {acc10, acc11}};
    for (int ms = 0; ms < 2; ms++) {
        for (int ns = 0; ns < 2; ns++) {
            int n = n0 + wn + ns * 16 + lm;
            float bval = bias[n];
            for (int r = 0; r < 4; r++) {
                int m = m0 + wm + ms * 16 + quad * 4 + r;
                float v = accs[ms][ns][r] + bval;
                if (EPI == 0) {
                    ((unsigned short*)outp)[(size_t)m * N + n] = f2bf(v);
                } else {
                    ((float*)outp)[(size_t)m * N + n] =
                        v * gscale[m] + resid[(size_t)m * N + n];
                }
            }
        }
    }
}

// ---------------- fused per-row attention -----------------------------------
__global__ __launch_bounds__(256) void k_attn(
    const float* __restrict__ gene, const unsigned short* __restrict__ QKb,
    const void* __restrict__ maskbuf, const int* __restrict__ modep,
    const float* __restrict__ mask_n,
    unsigned short* __restrict__ G, float* __restrict__ gscale,
    float* __restrict__ aw_out)
{
    __shared__ __align__(16) unsigned short glb[32 * 520];  // gene row-block, bf16, pitch 520
    __shared__ __align__(16) unsigned short qka[16 * 520];  // qk as MFMA A rows (0,1 live)
    __shared__ __align__(16) float sp[4 * 64];              // per-wave score partials
    __shared__ __align__(16) float wls[64];                 // softmax weights [h*32+s]
    __shared__ int msk_s[32];
    __shared__ int inv_s;

    int b = blockIdx.x, t = threadIdx.x;

    // stage gene[b] fp32 -> bf16 LDS (fully coalesced 32B/lane)
    const float4* gp = (const float4*)(gene + (size_t)b * (SNB * DM));
    for (int it = 0; it < 8; it++) {
        float4 v0 = gp[t * 2 + it * 512];
        float4 v1 = gp[t * 2 + 1 + it * 512];
        int s = (t >> 6) + it * 4;
        int col = (t & 63) * 8;
        bf16x8 pk;
        pk[0] = (short)f2bf(v0.x); pk[1] = (short)f2bf(v0.y);
        pk[2] = (short)f2bf(v0.z); pk[3] = (short)f2bf(v0.w);
        pk[4] = (short)f2bf(v1.x); pk[5] = (short)f2bf(v1.y);
        pk[6] = (short)f2bf(v1.z); pk[7] = (short)f2bf(v1.w);
        *(bf16x8*)(glb + s * 520 + col) = pk;
    }
    // stage qk row (bf16), rows 0..1 of the A operand
    {
        int h = (t * 4) >> 9, j = (t * 4) & 511;
        *(ushort4*)(qka + h * 520 + j) = *(const ushort4*)(QKb + (size_t)b * 1024 + t * 4);
    }
    // zero A rows 2..15 (avoid NaN garbage feeding MFMA)
    {
        unsigned long long* z = (unsigned long long*)(qka + 2 * 520);
        for (int i = t; i < 1820; i += 256) z[i] = 0ull;
    }
    // mask load (dtype per detector)
    int mode = *modep;
    if (t < 32) {
        size_t off = (size_t)b * 32 + t;
        int mv;
        if (mode == 1)      mv = ((const unsigned char*)maskbuf)[off] != 0;
        else if (mode == 2) mv = (((const float*)maskbuf)[off] != 0.0f);
        else                mv = (((const int*)maskbuf)[off] != 0);
        msk_s[t] = mv;
    }
    __syncthreads();

    if (t == 0) {
        int all = 1;
        for (int s = 0; s < 32; s++) all &= msk_s[s];
        inv_s = all;
        if (all) msk_s[0] = 0;                 // torch in-place fix: unmask slot 0
        gscale[b] = all ? 0.0f : mask_n[b];
    }

    // scores via MFMA, K split across the 4 waves
    {
        int w = t >> 6, l = t & 63, quad = l >> 4, lm = l & 15;
        f32x4 s0 = {0.f, 0.f, 0.f, 0.f}, s1 = {0.f, 0.f, 0.f, 0.f};
        int kb = w * 128;
#pragma unroll
        for (int kk = 0; kk < 4; kk++) {
            int k0 = kb + kk * 32;
            bf16x8 af = *(const bf16x8*)(qka + lm * 520 + k0 + quad * 8);
            bf16x8 b0 = *(const bf16x8*)(glb + lm * 520 + k0 + quad * 8);
            bf16x8 b1 = *(const bf16x8*)(glb + (16 + lm) * 520 + k0 + quad * 8);
            s0 = __builtin_amdgcn_mfma_f32_16x16x32_bf16(af, b0, s0, 0, 0, 0);
            s1 = __builtin_amdgcn_mfma_f32_16x16x32_bf16(af, b1, s1, 0, 0, 0);
        }
        if (quad == 0) {                       // D rows 0,1 = heads 0,1
            sp[w * 64 + lm] = s0[0];
            sp[w * 64 + 32 + lm] = s0[1];
            sp[w * 64 + 16 + lm] = s1[0];
            sp[w * 64 + 48 + lm] = s1[1];
        }
    }
    __syncthreads();

    // softmax over s per head (wave 0; lanes 0-31 = h0, 32-63 = h1)
    if (t < 64) {
        int s = t & 31;
        float v = sp[t] + sp[64 + t] + sp[128 + t] + sp[192 + t];
        int mk = msk_s[s];
        float vm = mk ? -1e30f : v;
        for (int off = 16; off > 0; off >>= 1) vm = fmaxf(vm, __shfl_xor(vm, off, 64));
        float ex = mk ? 0.0f : __expf(v - vm);
        float sm = ex;
        for (int off = 16; off > 0; off >>= 1) sm += __shfl_xor(sm, off, 64);
        wls[t] = ex / sm;
    }
    __syncthreads();

    if (t < 32) aw_out[(size_t)b * 32 + t] = 0.5f * (wls[t] + wls[32 + t]);

    // gbar[h,j] = sum_s w[h,s]*gene[s,j]  (each thread: one head, 4 j)
    {
        int h = t >> 7, jg = (t & 127) << 2;
        float a0 = 0.f, a1 = 0.f, a2 = 0.f, a3 = 0.f;
        const float* wrow = wls + h * 32;
        for (int s4 = 0; s4 < 8; s4++) {
            float4 wv = *(const float4*)(wrow + s4 * 4);
#pragma unroll
            for (int si = 0; si < 4; si++) {
                int s = s4 * 4 + si;
                ushort4 gv = *(const ushort4*)(glb + s * 520 + jg);
                float wq = (si == 0) ? wv.x : (si == 1) ? wv.y : (si == 2) ? wv.z : wv.w;
                a0 += wq * bf2f(gv.x); a1 += wq * bf2f(gv.y);
                a2 += wq * bf2f(gv.z); a3 += wq * bf2f(gv.w);
            }
        }
        ushort4 ov;
        ov.x = f2bf(a0); ov.y = f2bf(a1); ov.z = f2bf(a2); ov.w = f2bf(a3);
        *(ushort4*)(G + (size_t)b * 1024 + h * 512 + jg) = ov;
    }
}

extern "C" void kernel_launch(void* const* d_in, const int* in_sizes, int n_in,
                              void* d_out, int out_size, void* d_ws, size_t ws_size,
                              hipStream_t stream)
{
    const float* src   = (const float*)d_in[0];
    const float* gene  = (const float*)d_in[1];
    const void*  mask  = d_in[2];
    const float* maskn = (const float*)d_in[3];
    const float* Wq    = (const float*)d_in[4];
    const float* bq    = (const float*)d_in[5];
    const float* Wk    = (const float*)d_in[6];
    // d_in[7] = bk: cancels in softmax, unused
    const float* Wv    = (const float*)d_in[8];
    const float* bv    = (const float*)d_in[9];
    const float* Wout  = (const float*)d_in[10];
    const float* bout  = (const float*)d_in[11];

    float* out = (float*)d_out;
    float* aw  = out + (size_t)NB * DM;

    char* ws = (char*)d_ws;
    size_t off = 0;
    auto alloc = [&](size_t bytes) -> void* {
        void* p = ws + off;
        off = (off + bytes + 255) & ~((size_t)255);
        return p;
    };
    int* mode            = (int*)alloc(4);
    unsigned short* srcb = (unsigned short*)alloc((size_t)NB * DM * 2);   // 4 MiB
    unsigned short* Cb   = (unsigned short*)alloc((size_t)1024 * 512 * 2);// 1 MiB
    unsigned short* Db   = (unsigned short*)alloc((size_t)512 * 1024 * 2);// 1 MiB
    float* cb            = (float*)alloc(1024 * 4);
    float* ev            = (float*)alloc(512 * 4);
    unsigned short* QKb  = (unsigned short*)alloc((size_t)NB * 1024 * 2); // 8 MiB
    unsigned short* G    = (unsigned short*)alloc((size_t)NB * 1024 * 2); // 8 MiB
    float* gs            = (float*)alloc((size_t)NB * 4);

    k_detect<<<1, 256, 0, stream>>>((const unsigned int*)mask, mode);
    k_conv_src<<<(NB * DM / 4) / 256, 256, 0, stream>>>(src, srcb);
    k_precomp_cd<<<1024, 256, 0, stream>>>(Wq, Wk, Wv, Wout, Cb, Db);
    k_precomp_vec<<<6, 256, 0, stream>>>(Wk, bq, Wout, bv, bout, cb, ev);
    k_gemm_bt<0><<<(4096 / 64) * (1024 / 64), 256, 0, stream>>>(
        srcb, Cb, QKb, cb, nullptr, nullptr, 4096, 1024, 512);
    k_attn<<<NB, 256, 0, stream>>>(gene, QKb, mask, mode, maskn, G, gs, aw);
    k_gemm_bt<1><<<(4096 / 64) * (512 / 64), 256, 0, stream>>>(
        G, Db, out, ev, gs, src, 4096, 512, 1024);
}

// Round 2
// 461.355 us; speedup vs baseline: 1.1277x; 1.1277x over previous
//
#include <hip/hip_runtime.h>
#include <hip/hip_bf16.h>
#include <math.h>
#include <stdint.h>

// TGN attention node, algebraically restructured (K/V never materialized):
//   qk[b,h,:]  = C_h . source[b] + cb_h,   C = (1/16) Wk_h^T Wq_h   (bk cancels)
//   scores     = gene . qk, softmax over s
//   gbar[b,h]  = sum_s w[h,s] gene[b,s]    (sum w = 1 absorbs bv)
//   out        = ([gbar_0|gbar_1] @ D^T + e) * gate + source,  D = Wout_h Wv_h
// Round 2: MFMA-based C/D precompute (round-1 VALU version was ds_read-bound
// ~50us), fused prep kernel (7 -> 5 launches), attn LDS 51->35KB (4 blk/CU).

#define NB 4096
#define SNB 32
#define DM 512

typedef __attribute__((ext_vector_type(8))) short bf16x8;
typedef __attribute__((ext_vector_type(4))) float f32x4;

__device__ __forceinline__ unsigned short f2bf(float f) {
    union { float f; unsigned int u; } v; v.f = f;
    unsigned int u = v.u;
    return (unsigned short)((u + 0x7FFFu + ((u >> 16) & 1u)) >> 16);
}
__device__ __forceinline__ float bf2f(unsigned short s) {
    union { unsigned int u; float f; } v; v.u = ((unsigned int)s) << 16;
    return v.f;
}

// ---------------- fused prep: detect + cb/e + converts + transposes ---------
// blocks: [0] mask-dtype detect | [1,4] cb | [5,6] e | [7,262] WkT (x1/16)
//         [263,518] WvT | [519,774] WqT | [775,806] Wout->bf16 | [807,1062] src->bf16
__global__ __launch_bounds__(256) void k_prep(
    const float* __restrict__ src, const float* __restrict__ Wq,
    const float* __restrict__ bq, const float* __restrict__ Wk,
    const float* __restrict__ Wv, const float* __restrict__ Wout,
    const float* __restrict__ bv, const float* __restrict__ bout,
    const unsigned int* __restrict__ maskw,
    unsigned short* __restrict__ srcb, unsigned short* __restrict__ WkT,
    unsigned short* __restrict__ WqT, unsigned short* __restrict__ WvT,
    unsigned short* __restrict__ WoutB,
    float* __restrict__ cb, float* __restrict__ e, int* __restrict__ mode)
{
    __shared__ float tile[32][33];
    __shared__ int fF, fH;
    int bid = blockIdx.x, t = threadIdx.x;

    if (bid == 0) {                                   // mask dtype detect
        if (t == 0) { fF = 0; fH = 0; }
        __syncthreads();
        int lf = 0, lh = 0;
        for (int i = t; i < 32768; i += 256) {        // 128KB: in-bounds for u8/i32/f32
            unsigned int w = maskw[i];
            lf |= (w == 0x3F800000u);
            lh |= ((w & 0xFFFFFF00u) != 0u);
        }
        if (lf) atomicOr(&fF, 1);
        if (lh) atomicOr(&fH, 1);
        __syncthreads();
        if (t == 0) *mode = fF ? 2 : (fH ? 1 : 0);
        return;
    }
    if (bid <= 4) {                                   // cb[h*512+j]
        int idx = (bid - 1) * 256 + t;
        int h = idx >> 9, j = idx & 511;
        float a = 0.f;
        for (int i = 0; i < 256; i++)
            a += Wk[(size_t)(h * 256 + i) * 512 + j] * bq[h * 256 + i];
        cb[idx] = 0.0625f * a;
        return;
    }
    if (bid <= 6) {                                   // e[n] = Wout.bv + bout
        int n = (bid - 5) * 256 + t;
        const float4* wr = (const float4*)(Wout + (size_t)n * 512);
        const float4* bv4 = (const float4*)bv;
        float a = bout[n];
        for (int q = 0; q < 128; q++) {
            float4 wv = wr[q], vv = bv4[q];
            a += wv.x * vv.x + wv.y * vv.y + wv.z * vv.z + wv.w * vv.w;
        }
        e[n] = a;
        return;
    }
    if (bid < 775) {                                  // 32x32 transpose tiles
        const float* sm; unsigned short* dst; float scale; int tt;
        if (bid < 263)      { tt = bid - 7;   sm = Wk; dst = WkT; scale = 0.0625f; }
        else if (bid < 519) { tt = bid - 263; sm = Wv; dst = WvT; scale = 1.0f; }
        else                { tt = bid - 519; sm = Wq; dst = WqT; scale = 1.0f; }
        int i0 = (tt >> 4) << 5, j0 = (tt & 15) << 5;
        int r = t >> 3, c4 = (t & 7) << 2;
        float4 v = *(const float4*)(sm + (size_t)(i0 + r) * 512 + j0 + c4);
        tile[r][c4 + 0] = v.x; tile[r][c4 + 1] = v.y;
        tile[r][c4 + 2] = v.z; tile[r][c4 + 3] = v.w;
        __syncthreads();
        int jj = t >> 3, ig = (t & 7) << 2;
        int h = i0 >> 8, ib = i0 & 255;
        ushort4 o;
        o.x = f2bf(tile[ig + 0][jj] * scale);
        o.y = f2bf(tile[ig + 1][jj] * scale);
        o.z = f2bf(tile[ig + 2][jj] * scale);
        o.w = f2bf(tile[ig + 3][jj] * scale);
        // dst layout: [h][row j or m][i in head]  == flat h*131072 + row*256 + i
        *(ushort4*)(dst + (size_t)h * 131072 + (size_t)(j0 + jj) * 256 + ib + ig) = o;
        return;
    }
    if (bid < 807) {                                  // Wout fp32->bf16 (row-major)
        int base = (bid - 775) * 2048;
        for (int q = 0; q < 8; q++) {
            int idx = base + q * 256 + t;
            float4 v = ((const float4*)Wout)[idx];
            ushort4 o;
            o.x = f2bf(v.x); o.y = f2bf(v.y); o.z = f2bf(v.z); o.w = f2bf(v.w);
            ((ushort4*)WoutB)[idx] = o;
        }
        return;
    }
    {                                                 // source fp32->bf16
        int base = (bid - 807) * 2048;
        for (int q = 0; q < 8; q++) {
            int idx = base + q * 256 + t;
            float4 v = ((const float4*)src)[idx];
            ushort4 o;
            o.x = f2bf(v.x); o.y = f2bf(v.y); o.z = f2bf(v.z); o.w = f2bf(v.w);
            ((ushort4*)srcb)[idx] = o;
        }
    }
}

// ---------------- C and D via MFMA (256 blocks, K=256) ----------------------
// bid<128: C[h*512+j][m] = sum_i WkT[h*512+j][i] * WqT[h][m][i]
// else:    D[n][h*512+j] = sum_i WoutB[n][h*256+i] * WvT[h*512+j][i]
__global__ __launch_bounds__(256) void k_cd(
    const unsigned short* __restrict__ WkT, const unsigned short* __restrict__ WqT,
    const unsigned short* __restrict__ WoutB, const unsigned short* __restrict__ WvT,
    unsigned short* __restrict__ C, unsigned short* __restrict__ D)
{
    __shared__ __align__(16) unsigned short As[64 * 40];
    __shared__ __align__(16) unsigned short Bs[64 * 40];
    int bid = blockIdx.x, t = threadIdx.x;
    const unsigned short *A, *Bt;
    unsigned short* outp;
    int lda, ldb, ldo;
    if (bid < 128) {
        int m0 = (bid >> 3) << 6, n0 = (bid & 7) << 6, h = m0 >> 9;
        A = WkT + (size_t)m0 * 256; lda = 256;
        Bt = WqT + (size_t)h * 131072 + (size_t)n0 * 256; ldb = 256;
        outp = C + (size_t)m0 * 512 + n0; ldo = 512;
    } else {
        int b2 = bid - 128;
        int m0 = (b2 >> 4) << 6, n0 = (b2 & 15) << 6, h = n0 >> 9;
        A = WoutB + (size_t)m0 * 512 + h * 256; lda = 512;
        Bt = WvT + (size_t)n0 * 256; ldb = 256;
        outp = D + (size_t)m0 * 1024 + n0; ldo = 1024;
    }
    int w = t >> 6, l = t & 63;
    int wm = (w >> 1) << 5, wn = (w & 1) << 5;
    int quad = l >> 4, lm = l & 15;
    f32x4 acc00 = {0.f,0.f,0.f,0.f}, acc01 = {0.f,0.f,0.f,0.f};
    f32x4 acc10 = {0.f,0.f,0.f,0.f}, acc11 = {0.f,0.f,0.f,0.f};
    int srow = t >> 2, spart = t & 3;
    const unsigned short* ag = A + (size_t)srow * lda + spart * 8;
    const unsigned short* bg = Bt + (size_t)srow * ldb + spart * 8;
    unsigned short* asl = As + srow * 40 + spart * 8;
    unsigned short* bsl = Bs + srow * 40 + spart * 8;
    for (int k0 = 0; k0 < 256; k0 += 32) {
        *(bf16x8*)asl = *(const bf16x8*)ag;
        *(bf16x8*)bsl = *(const bf16x8*)bg;
        ag += 32; bg += 32;
        __syncthreads();
        bf16x8 a0 = *(const bf16x8*)(As + (wm + lm) * 40 + quad * 8);
        bf16x8 a1 = *(const bf16x8*)(As + (wm + 16 + lm) * 40 + quad * 8);
        bf16x8 b0 = *(const bf16x8*)(Bs + (wn + lm) * 40 + quad * 8);
        bf16x8 b1 = *(const bf16x8*)(Bs + (wn + 16 + lm) * 40 + quad * 8);
        acc00 = __builtin_amdgcn_mfma_f32_16x16x32_bf16(a0, b0, acc00, 0, 0, 0);
        acc01 = __builtin_amdgcn_mfma_f32_16x16x32_bf16(a0, b1, acc01, 0, 0, 0);
        acc10 = __builtin_amdgcn_mfma_f32_16x16x32_bf16(a1, b0, acc10, 0, 0, 0);
        acc11 = __builtin_amdgcn_mfma_f32_16x16x32_bf16(a1, b1, acc11, 0, 0, 0);
        __syncthreads();
    }
    f32x4 accs[2][2] = {{acc00, acc01}, {acc10, acc11}};
    for (int ms = 0; ms < 2; ms++)
        for (int ns = 0; ns < 2; ns++)
            for (int r = 0; r < 4; r++)
                outp[(size_t)(wm + ms * 16 + quad * 4 + r) * ldo + wn + ns * 16 + lm] =
                    f2bf(accs[ms][ns][r]);
}

// ---------------- MFMA GEMM, B^T layout: out[m,n] = sum_k A[m,k]*Bt[n,k] ----
// EPI 0: bf16 out = acc + bias[n]  (QK)
// EPI 1: f32 out = (acc + bias[n]) * gscale[m] + resid[m,n]  (final)
template <int EPI>
__global__ __launch_bounds__(256) void k_gemm_bt(
    const unsigned short* __restrict__ A, const unsigned short* __restrict__ Bt,
    void* __restrict__ outp, const float* __restrict__ bias,
    const float* __restrict__ gscale, const float* __restrict__ resid,
    int M, int N, int K)
{
    __shared__ __align__(16) unsigned short As[64 * 40];
    __shared__ __align__(16) unsigned short Bs[64 * 40];
    int nt = N >> 6;
    int m0 = ((int)blockIdx.x / nt) << 6;
    int n0 = ((int)blockIdx.x % nt) << 6;
    int t = threadIdx.x;
    int w = t >> 6, l = t & 63;
    int wm = (w >> 1) << 5, wn = (w & 1) << 5;
    int quad = l >> 4, lm = l & 15;

    f32x4 acc00 = {0.f,0.f,0.f,0.f}, acc01 = {0.f,0.f,0.f,0.f};
    f32x4 acc10 = {0.f,0.f,0.f,0.f}, acc11 = {0.f,0.f,0.f,0.f};

    int srow = t >> 2, spart = t & 3;
    const unsigned short* ag = A + (size_t)(m0 + srow) * K + spart * 8;
    const unsigned short* bg = Bt + (size_t)(n0 + srow) * K + spart * 8;
    unsigned short* asl = As + srow * 40 + spart * 8;
    unsigned short* bsl = Bs + srow * 40 + spart * 8;

    for (int k0 = 0; k0 < K; k0 += 32) {
        *(bf16x8*)asl = *(const bf16x8*)ag;
        *(bf16x8*)bsl = *(const bf16x8*)bg;
        ag += 32; bg += 32;
        __syncthreads();
        bf16x8 a0 = *(const bf16x8*)(As + (wm + lm) * 40 + quad * 8);
        bf16x8 a1 = *(const bf16x8*)(As + (wm + 16 + lm) * 40 + quad * 8);
        bf16x8 b0 = *(const bf16x8*)(Bs + (wn + lm) * 40 + quad * 8);
        bf16x8 b1 = *(const bf16x8*)(Bs + (wn + 16 + lm) * 40 + quad * 8);
        acc00 = __builtin_amdgcn_mfma_f32_16x16x32_bf16(a0, b0, acc00, 0, 0, 0);
        acc01 = __builtin_amdgcn_mfma_f32_16x16x32_bf16(a0, b1, acc01, 0, 0, 0);
        acc10 = __builtin_amdgcn_mfma_f32_16x16x32_bf16(a1, b0, acc10, 0, 0, 0);
        acc11 = __builtin_amdgcn_mfma_f32_16x16x32_bf16(a1, b1, acc11, 0, 0, 0);
        __syncthreads();
    }
    f32x4 accs[2][2] = {{acc00, acc01}, {acc10, acc11}};
    for (int ms = 0; ms < 2; ms++) {
        for (int ns = 0; ns < 2; ns++) {
            int n = n0 + wn + ns * 16 + lm;
            float bval = bias[n];
            for (int r = 0; r < 4; r++) {
                int m = m0 + wm + ms * 16 + quad * 4 + r;
                float v = accs[ms][ns][r] + bval;
                if (EPI == 0) {
                    ((unsigned short*)outp)[(size_t)m * N + n] = f2bf(v);
                } else {
                    ((float*)outp)[(size_t)m * N + n] =
                        v * gscale[m] + resid[(size_t)m * N + n];
                }
            }
        }
    }
}

// ---------------- fused per-row attention -----------------------------------
__global__ __launch_bounds__(256) void k_attn(
    const float* __restrict__ gene, const unsigned short* __restrict__ QKb,
    const void* __restrict__ maskbuf, const int* __restrict__ modep,
    const float* __restrict__ mask_n,
    unsigned short* __restrict__ G, float* __restrict__ gscale,
    float* __restrict__ aw_out)
{
    __shared__ __align__(16) unsigned short glb[32 * 520];  // gene block bf16
    __shared__ __align__(16) float sp[4 * 64];
    __shared__ __align__(16) float wls[64];
    __shared__ int msk_s[32];

    int b = blockIdx.x, t = threadIdx.x;
    int w = t >> 6, l = t & 63, quad = l >> 4, lm = l & 15;

    // A-fragment (qk rows; only m=0,1 live) straight from global to registers
    bf16x8 af[4];
    {
        const unsigned short* qp = QKb + (size_t)b * 1024 + (size_t)lm * 512
                                 + w * 128 + quad * 8;
#pragma unroll
        for (int kk = 0; kk < 4; kk++) {
            bf16x8 z = {0,0,0,0,0,0,0,0};
            af[kk] = (lm < 2) ? *(const bf16x8*)(qp + kk * 32) : z;
        }
    }

    // stage gene[b] fp32 -> bf16 LDS
    const float4* gp = (const float4*)(gene + (size_t)b * (SNB * DM));
    for (int it = 0; it < 8; it++) {
        float4 v0 = gp[t * 2 + it * 512];
        float4 v1 = gp[t * 2 + 1 + it * 512];
        int s = (t >> 6) + it * 4;
        int col = (t & 63) * 8;
        bf16x8 pk;
        pk[0] = (short)f2bf(v0.x); pk[1] = (short)f2bf(v0.y);
        pk[2] = (short)f2bf(v0.z); pk[3] = (short)f2bf(v0.w);
        pk[4] = (short)f2bf(v1.x); pk[5] = (short)f2bf(v1.y);
        pk[6] = (short)f2bf(v1.z); pk[7] = (short)f2bf(v1.w);
        *(bf16x8*)(glb + s * 520 + col) = pk;
    }
    // mask load
    int mode = *modep;
    if (t < 32) {
        size_t moff = (size_t)b * 32 + t;
        int mv;
        if (mode == 1)      mv = ((const unsigned char*)maskbuf)[moff] != 0;
        else if (mode == 2) mv = (((const float*)maskbuf)[moff] != 0.0f);
        else                mv = (((const int*)maskbuf)[moff] != 0);
        msk_s[t] = mv;
    }
    __syncthreads();

    if (t == 0) {
        int all = 1;
        for (int s = 0; s < 32; s++) all &= msk_s[s];
        if (all) msk_s[0] = 0;                 // torch in-place fix
        gscale[b] = all ? 0.0f : mask_n[b];
    }

    // scores via MFMA, K split across 4 waves
    {
        f32x4 s0 = {0.f,0.f,0.f,0.f}, s1 = {0.f,0.f,0.f,0.f};
        int kb = w * 128;
#pragma unroll
        for (int kk = 0; kk < 4; kk++) {
            int k0 = kb + kk * 32;
            bf16x8 b0 = *(const bf16x8*)(glb + lm * 520 + k0 + quad * 8);
            bf16x8 b1 = *(const bf16x8*)(glb + (16 + lm) * 520 + k0 + quad * 8);
            s0 = __builtin_amdgcn_mfma_f32_16x16x32_bf16(af[kk], b0, s0, 0, 0, 0);
            s1 = __builtin_amdgcn_mfma_f32_16x16x32_bf16(af[kk], b1, s1, 0, 0, 0);
        }
        if (quad == 0) {
            sp[w * 64 + lm] = s0[0];
            sp[w * 64 + 32 + lm] = s0[1];
            sp[w * 64 + 16 + lm] = s1[0];
            sp[w * 64 + 48 + lm] = s1[1];
        }
    }
    __syncthreads();

    // softmax (wave 0: lanes 0-31 head0, 32-63 head1)
    if (t < 64) {
        int s = t & 31;
        float v = sp[t] + sp[64 + t] + sp[128 + t] + sp[192 + t];
        int mk = msk_s[s];
        float vm = mk ? -1e30f : v;
        for (int off = 16; off > 0; off >>= 1) vm = fmaxf(vm, __shfl_xor(vm, off, 64));
        float ex = mk ? 0.0f : __expf(v - vm);
        float sm = ex;
        for (int off = 16; off > 0; off >>= 1) sm += __shfl_xor(sm, off, 64);
        wls[t] = ex / sm;
    }
    __syncthreads();

    if (t < 32) aw_out[(size_t)b * 32 + t] = 0.5f * (wls[t] + wls[32 + t]);

    // gbar[h,j] = sum_s w[h,s]*gene[s,j]
    {
        int h = t >> 7, jg = (t & 127) << 2;
        float a0 = 0.f, a1 = 0.f, a2 = 0.f, a3 = 0.f;
        const float* wrow = wls + h * 32;
        for (int s4 = 0; s4 < 8; s4++) {
            float4 wv = *(const float4*)(wrow + s4 * 4);
#pragma unroll
            for (int si = 0; si < 4; si++) {
                int s = s4 * 4 + si;
                ushort4 gv = *(const ushort4*)(glb + s * 520 + jg);
                float wq = (si == 0) ? wv.x : (si == 1) ? wv.y : (si == 2) ? wv.z : wv.w;
                a0 += wq * bf2f(gv.x); a1 += wq * bf2f(gv.y);
                a2 += wq * bf2f(gv.z); a3 += wq * bf2f(gv.w);
            }
        }
        ushort4 ov;
        ov.x = f2bf(a0); ov.y = f2bf(a1); ov.z = f2bf(a2); ov.w = f2bf(a3);
        *(ushort4*)(G + (size_t)b * 1024 + h * 512 + jg) = ov;
    }
}

extern "C" void kernel_launch(void* const* d_in, const int* in_sizes, int n_in,
                              void* d_out, int out_size, void* d_ws, size_t ws_size,
                              hipStream_t stream)
{
    const float* src   = (const float*)d_in[0];
    const float* gene  = (const float*)d_in[1];
    const void*  mask  = d_in[2];
    const float* maskn = (const float*)d_in[3];
    const float* Wq    = (const float*)d_in[4];
    const float* bq    = (const float*)d_in[5];
    const float* Wk    = (const float*)d_in[6];
    // d_in[7] = bk: cancels in softmax, unused
    const float* Wv    = (const float*)d_in[8];
    const float* bv    = (const float*)d_in[9];
    const float* Wout  = (const float*)d_in[10];
    const float* bout  = (const float*)d_in[11];

    float* out = (float*)d_out;
    float* aw  = out + (size_t)NB * DM;

    char* ws = (char*)d_ws;
    size_t off = 0;
    auto alloc = [&](size_t bytes) -> void* {
        void* p = ws + off;
        off = (off + bytes + 255) & ~((size_t)255);
        return p;
    };
    int* mode            = (int*)alloc(4);
    unsigned short* srcb = (unsigned short*)alloc((size_t)NB * DM * 2);    // 4 MiB
    unsigned short* WkT  = (unsigned short*)alloc((size_t)1024 * 256 * 2); // 512 KiB
    unsigned short* WqT  = (unsigned short*)alloc((size_t)1024 * 256 * 2);
    unsigned short* WvT  = (unsigned short*)alloc((size_t)1024 * 256 * 2);
    unsigned short* WoB  = (unsigned short*)alloc((size_t)512 * 512 * 2);
    unsigned short* Cb   = (unsigned short*)alloc((size_t)1024 * 512 * 2); // 1 MiB
    unsigned short* Db   = (unsigned short*)alloc((size_t)512 * 1024 * 2); // 1 MiB
    float* cb            = (float*)alloc(1024 * 4);
    float* ev            = (float*)alloc(512 * 4);
    unsigned short* QKb  = (unsigned short*)alloc((size_t)NB * 1024 * 2);  // 8 MiB
    unsigned short* G    = (unsigned short*)alloc((size_t)NB * 1024 * 2);  // 8 MiB
    float* gs            = (float*)alloc((size_t)NB * 4);

    k_prep<<<1063, 256, 0, stream>>>(src, Wq, bq, Wk, Wv, Wout, bv, bout,
                                     (const unsigned int*)mask,
                                     srcb, WkT, WqT, WvT, WoB, cb, ev, mode);
    k_cd<<<256, 256, 0, stream>>>(WkT, WqT, WoB, WvT, Cb, Db);
    k_gemm_bt<0><<<(4096 / 64) * (1024 / 64), 256, 0, stream>>>(
        srcb, Cb, QKb, cb, nullptr, nullptr, 4096, 1024, 512);
    k_attn<<<NB, 256, 0, stream>>>(gene, QKb, mask, mode, maskn, G, gs, aw);
    k_gemm_bt<1><<<(4096 / 64) * (512 / 64), 256, 0, stream>>>(
        G, Db, out, ev, gs, src, 4096, 512, 1024);
}

// Round 4
// 450.777 us; speedup vs baseline: 1.1541x; 1.0235x over previous
//
#include <hip/hip_runtime.h>
#include <hip/hip_bf16.h>
#include <math.h>
#include <stdint.h>

// TGN attention node, algebraically restructured (K/V never materialized):
//   qk[b,h,:]  = C_h . source[b] + cb_h,   C = (1/16) Wk_h^T Wq_h   (bk cancels)
//   scores     = gene . qk, softmax over s
//   gbar[b,h]  = sum_s w[h,s] gene[b,s]    (sum w = 1 absorbs bv)
//   out        = ([gbar_0|gbar_1] @ D^T + e) * gate + source,  D = Wout_h Wv_h
// Round 4: fix round-3 bug — C-tile Wk column index must be (j0 & 511): C's
// row index is h*512+j but Wk is only 512 wide. (D branch already masked.)

#define NB 4096
#define SNB 32
#define DM 512

typedef __attribute__((ext_vector_type(8))) short bf16x8;
typedef __attribute__((ext_vector_type(4))) float f32x4;

__device__ __forceinline__ unsigned short f2bf(float f) {
    union { float f; unsigned int u; } v; v.f = f;
    unsigned int u = v.u;
    return (unsigned short)((u + 0x7FFFu + ((u >> 16) & 1u)) >> 16);
}
__device__ __forceinline__ float bf2f(unsigned short s) {
    union { unsigned int u; float f; } v; v.u = ((unsigned int)s) << 16;
    return v.f;
}

// ---------------- fused prep + C/D precompute -------------------------------
// blocks: [0] mask-dtype detect | [1,4] cb | [5,6] e | [7,262] src->bf16
//         [263,390] C tiles (MFMA, inline transpose) | [391,518] D tiles
__global__ __launch_bounds__(256) void k_prep_cd(
    const float* __restrict__ src, const float* __restrict__ Wq,
    const float* __restrict__ bq, const float* __restrict__ Wk,
    const float* __restrict__ Wv, const float* __restrict__ Wout,
    const float* __restrict__ bv, const float* __restrict__ bout,
    const unsigned int* __restrict__ maskw,
    unsigned short* __restrict__ srcb, float* __restrict__ cb,
    float* __restrict__ e, int* __restrict__ mode,
    unsigned short* __restrict__ C, unsigned short* __restrict__ D)
{
    __shared__ __align__(16) unsigned short As[64 * 40];
    __shared__ __align__(16) unsigned short Bs[64 * 40];
    __shared__ int fF, fH;
    int bid = blockIdx.x, t = threadIdx.x;

    if (bid == 0) {                                   // mask dtype detect
        if (t == 0) { fF = 0; fH = 0; }
        __syncthreads();
        int lf = 0, lh = 0;
        for (int i = t; i < 32768; i += 256) {        // 128KB: in-bounds u8/i32/f32
            unsigned int w = maskw[i];
            lf |= (w == 0x3F800000u);
            lh |= ((w & 0xFFFFFF00u) != 0u);
        }
        if (lf) atomicOr(&fF, 1);
        if (lh) atomicOr(&fH, 1);
        __syncthreads();
        if (t == 0) *mode = fF ? 2 : (fH ? 1 : 0);
        return;
    }
    if (bid <= 4) {                                   // cb[h*512+j] = Wk^T bq / 16
        int idx = (bid - 1) * 256 + t;
        int h = idx >> 9, j = idx & 511;
        float a = 0.f;
        for (int i = 0; i < 256; i++)
            a += Wk[(size_t)(h * 256 + i) * 512 + j] * bq[h * 256 + i];
        cb[idx] = 0.0625f * a;
        return;
    }
    if (bid <= 6) {                                   // e[n] = Wout.bv + bout
        int n = (bid - 5) * 256 + t;
        const float4* wr = (const float4*)(Wout + (size_t)n * 512);
        const float4* bv4 = (const float4*)bv;
        float a = bout[n];
        for (int q = 0; q < 128; q++) {
            float4 wv = wr[q], vv = bv4[q];
            a += wv.x * vv.x + wv.y * vv.y + wv.z * vv.z + wv.w * vv.w;
        }
        e[n] = a;
        return;
    }
    if (bid < 263) {                                  // source fp32->bf16
        int base = (bid - 7) * 2048;
        for (int q = 0; q < 8; q++) {
            int idx = base + q * 256 + t;
            float4 v = ((const float4*)src)[idx];
            ushort4 o;
            o.x = f2bf(v.x); o.y = f2bf(v.y); o.z = f2bf(v.z); o.w = f2bf(v.w);
            ((ushort4*)srcb)[idx] = o;
        }
        return;
    }

    // ---- C/D 64x64 MFMA tiles, K=256 (per-head), transpose during staging --
    int w = t >> 6, l = t & 63;
    int wm = (w >> 1) << 5, wn = (w & 1) << 5;
    int quad = l >> 4, lm = l & 15;
    int sj = t & 63, si8 = (t >> 6) << 3;             // transpose-staging map
    f32x4 acc00 = {0.f,0.f,0.f,0.f}, acc01 = {0.f,0.f,0.f,0.f};
    f32x4 acc10 = {0.f,0.f,0.f,0.f}, acc11 = {0.f,0.f,0.f,0.f};

    unsigned short* outp;
    int ldo;
    if (bid < 391) {                                  // C[j0..][m0..]
        int tt = bid - 263;
        int j0 = (tt >> 3) << 6, m0 = (tt & 7) << 6;
        int jc = j0 & 511;                            // Wk column (per-head j)
        int ib = (j0 >> 9) << 8;                      // head i-range base
        for (int ic = 0; ic < 8; ic++) {
            int i0 = ib + ic * 32;
            bf16x8 av, bw;
#pragma unroll
            for (int q = 0; q < 8; q++) {             // coalesced row-segment loads
                av[q] = (short)f2bf(Wk[(size_t)(i0 + si8 + q) * 512 + jc + sj] * 0.0625f);
                bw[q] = (short)f2bf(Wq[(size_t)(i0 + si8 + q) * 512 + m0 + sj]);
            }
            *(bf16x8*)(As + sj * 40 + si8) = av;      // transposed, conflict-free b128
            *(bf16x8*)(Bs + sj * 40 + si8) = bw;
            __syncthreads();
            bf16x8 a0 = *(const bf16x8*)(As + (wm + lm) * 40 + quad * 8);
            bf16x8 a1 = *(const bf16x8*)(As + (wm + 16 + lm) * 40 + quad * 8);
            bf16x8 b0 = *(const bf16x8*)(Bs + (wn + lm) * 40 + quad * 8);
            bf16x8 b1 = *(const bf16x8*)(Bs + (wn + 16 + lm) * 40 + quad * 8);
            acc00 = __builtin_amdgcn_mfma_f32_16x16x32_bf16(a0, b0, acc00, 0, 0, 0);
            acc01 = __builtin_amdgcn_mfma_f32_16x16x32_bf16(a0, b1, acc01, 0, 0, 0);
            acc10 = __builtin_amdgcn_mfma_f32_16x16x32_bf16(a1, b0, acc10, 0, 0, 0);
            acc11 = __builtin_amdgcn_mfma_f32_16x16x32_bf16(a1, b1, acc11, 0, 0, 0);
            __syncthreads();
        }
        outp = C + (size_t)j0 * 512 + m0; ldo = 512;
    } else {                                          // D[n0..][jh0..]
        int tt = bid - 391;
        int n0 = (tt >> 4) << 6, jh0 = (tt & 15) << 6;
        int jc0 = jh0 & 511;
        int ib = (jh0 >> 9) << 8;
        int ra = t >> 2, ca = (t & 3) << 3;           // direct-staging map (A)
        for (int ic = 0; ic < 8; ic++) {
            int i0 = ib + ic * 32;
            {                                         // A = Wout rows (no transpose)
                const float4* p = (const float4*)(Wout + (size_t)(n0 + ra) * 512 + i0 + ca);
                float4 v0 = p[0], v1 = p[1];
                bf16x8 av;
                av[0] = (short)f2bf(v0.x); av[1] = (short)f2bf(v0.y);
                av[2] = (short)f2bf(v0.z); av[3] = (short)f2bf(v0.w);
                av[4] = (short)f2bf(v1.x); av[5] = (short)f2bf(v1.y);
                av[6] = (short)f2bf(v1.z); av[7] = (short)f2bf(v1.w);
                *(bf16x8*)(As + ra * 40 + ca) = av;
            }
            bf16x8 bw;
#pragma unroll
            for (int q = 0; q < 8; q++)               // B = Wv^T via transpose staging
                bw[q] = (short)f2bf(Wv[(size_t)(i0 + si8 + q) * 512 + jc0 + sj]);
            *(bf16x8*)(Bs + sj * 40 + si8) = bw;
            __syncthreads();
            bf16x8 a0 = *(const bf16x8*)(As + (wm + lm) * 40 + quad * 8);
            bf16x8 a1 = *(const bf16x8*)(As + (wm + 16 + lm) * 40 + quad * 8);
            bf16x8 b0 = *(const bf16x8*)(Bs + (wn + lm) * 40 + quad * 8);
            bf16x8 b1 = *(const bf16x8*)(Bs + (wn + 16 + lm) * 40 + quad * 8);
            acc00 = __builtin_amdgcn_mfma_f32_16x16x32_bf16(a0, b0, acc00, 0, 0, 0);
            acc01 = __builtin_amdgcn_mfma_f32_16x16x32_bf16(a0, b1, acc01, 0, 0, 0);
            acc10 = __builtin_amdgcn_mfma_f32_16x16x32_bf16(a1, b0, acc10, 0, 0, 0);
            acc11 = __builtin_amdgcn_mfma_f32_16x16x32_bf16(a1, b1, acc11, 0, 0, 0);
            __syncthreads();
        }
        outp = D + (size_t)n0 * 1024 + jh0; ldo = 1024;
    }
    f32x4 accs[2][2] = {{acc00, acc01}, {acc10, acc11}};
    for (int ms = 0; ms < 2; ms++)
        for (int ns = 0; ns < 2; ns++)
            for (int r = 0; r < 4; r++)
                outp[(size_t)(wm + ms * 16 + quad * 4 + r) * ldo + wn + ns * 16 + lm] =
                    f2bf(accs[ms][ns][r]);
}

// ---------------- MFMA GEMM, B^T layout, BK=64: out[m,n]=sum_k A[m,k]Bt[n,k]
// EPI 0: bf16 out = acc + bias[n]  (QK)
// EPI 1: f32 out = (acc + bias[n]) * gscale[m] + resid[m,n]  (final)
template <int EPI>
__global__ __launch_bounds__(256) void k_gemm_bt(
    const unsigned short* __restrict__ A, const unsigned short* __restrict__ Bt,
    void* __restrict__ outp, const float* __restrict__ bias,
    const float* __restrict__ gscale, const float* __restrict__ resid,
    int M, int N, int K)
{
    __shared__ __align__(16) unsigned short As[2][64 * 40];
    __shared__ __align__(16) unsigned short Bs[2][64 * 40];
    int nt = N >> 6;
    int m0 = ((int)blockIdx.x / nt) << 6;
    int n0 = ((int)blockIdx.x % nt) << 6;
    int t = threadIdx.x;
    int w = t >> 6, l = t & 63;
    int wm = (w >> 1) << 5, wn = (w & 1) << 5;
    int quad = l >> 4, lm = l & 15;

    f32x4 acc00 = {0.f,0.f,0.f,0.f}, acc01 = {0.f,0.f,0.f,0.f};
    f32x4 acc10 = {0.f,0.f,0.f,0.f}, acc11 = {0.f,0.f,0.f,0.f};

    int srow = t >> 2, spart = t & 3;
    int chunk = spart >> 1, coff = (spart & 1) << 4;
    const unsigned short* ag = A + (size_t)(m0 + srow) * K + spart * 16;
    const unsigned short* bg = Bt + (size_t)(n0 + srow) * K + spart * 16;
    unsigned short* asl = &As[chunk][srow * 40 + coff];
    unsigned short* bsl = &Bs[chunk][srow * 40 + coff];

    for (int k0 = 0; k0 < K; k0 += 64) {
        *(bf16x8*)asl       = *(const bf16x8*)ag;
        *(bf16x8*)(asl + 8) = *(const bf16x8*)(ag + 8);
        *(bf16x8*)bsl       = *(const bf16x8*)bg;
        *(bf16x8*)(bsl + 8) = *(const bf16x8*)(bg + 8);
        ag += 64; bg += 64;
        __syncthreads();
#pragma unroll
        for (int c = 0; c < 2; c++) {
            bf16x8 a0 = *(const bf16x8*)(&As[c][(wm + lm) * 40 + quad * 8]);
            bf16x8 a1 = *(const bf16x8*)(&As[c][(wm + 16 + lm) * 40 + quad * 8]);
            bf16x8 b0 = *(const bf16x8*)(&Bs[c][(wn + lm) * 40 + quad * 8]);
            bf16x8 b1 = *(const bf16x8*)(&Bs[c][(wn + 16 + lm) * 40 + quad * 8]);
            acc00 = __builtin_amdgcn_mfma_f32_16x16x32_bf16(a0, b0, acc00, 0, 0, 0);
            acc01 = __builtin_amdgcn_mfma_f32_16x16x32_bf16(a0, b1, acc01, 0, 0, 0);
            acc10 = __builtin_amdgcn_mfma_f32_16x16x32_bf16(a1, b0, acc10, 0, 0, 0);
            acc11 = __builtin_amdgcn_mfma_f32_16x16x32_bf16(a1, b1, acc11, 0, 0, 0);
        }
        __syncthreads();
    }
    f32x4 accs[2][2] = {{acc00, acc01}, {acc10, acc11}};
    for (int ms = 0; ms < 2; ms++) {
        for (int ns = 0; ns < 2; ns++) {
            int n = n0 + wn + ns * 16 + lm;
            float bval = bias[n];
            for (int r = 0; r < 4; r++) {
                int m = m0 + wm + ms * 16 + quad * 4 + r;
                float v = accs[ms][ns][r] + bval;
                if (EPI == 0) {
                    ((unsigned short*)outp)[(size_t)m * N + n] = f2bf(v);
                } else {
                    ((float*)outp)[(size_t)m * N + n] =
                        v * gscale[m] + resid[(size_t)m * N + n];
                }
            }
        }
    }
}

// ---------------- fused per-row attention -----------------------------------
__global__ __launch_bounds__(256) void k_attn(
    const float* __restrict__ gene, const unsigned short* __restrict__ QKb,
    const void* __restrict__ maskbuf, const int* __restrict__ modep,
    const float* __restrict__ mask_n,
    unsigned short* __restrict__ G, float* __restrict__ gscale,
    float* __restrict__ aw_out)
{
    __shared__ __align__(16) unsigned short glb[32 * 520];
    __shared__ __align__(16) float sp[4 * 64];
    __shared__ __align__(16) float wls[64];
    __shared__ int msk_s[32];

    int b = blockIdx.x, t = threadIdx.x;
    int w = t >> 6, l = t & 63, quad = l >> 4, lm = l & 15;

    bf16x8 af[4];
    {
        const unsigned short* qp = QKb + (size_t)b * 1024 + (size_t)lm * 512
                                 + w * 128 + quad * 8;
#pragma unroll
        for (int kk = 0; kk < 4; kk++) {
            bf16x8 z = {0,0,0,0,0,0,0,0};
            af[kk] = (lm < 2) ? *(const bf16x8*)(qp + kk * 32) : z;
        }
    }

    const float4* gp = (const float4*)(gene + (size_t)b * (SNB * DM));
    for (int it = 0; it < 8; it++) {
        float4 v0 = gp[t * 2 + it * 512];
        float4 v1 = gp[t * 2 + 1 + it * 512];
        int s = (t >> 6) + it * 4;
        int col = (t & 63) * 8;
        bf16x8 pk;
        pk[0] = (short)f2bf(v0.x); pk[1] = (short)f2bf(v0.y);
        pk[2] = (short)f2bf(v0.z); pk[3] = (short)f2bf(v0.w);
        pk[4] = (short)f2bf(v1.x); pk[5] = (short)f2bf(v1.y);
        pk[6] = (short)f2bf(v1.z); pk[7] = (short)f2bf(v1.w);
        *(bf16x8*)(glb + s * 520 + col) = pk;
    }
    int mode = *modep;
    if (t < 32) {
        size_t moff = (size_t)b * 32 + t;
        int mv;
        if (mode == 1)      mv = ((const unsigned char*)maskbuf)[moff] != 0;
        else if (mode == 2) mv = (((const float*)maskbuf)[moff] != 0.0f);
        else                mv = (((const int*)maskbuf)[moff] != 0);
        msk_s[t] = mv;
    }
    __syncthreads();

    if (t == 0) {
        int all = 1;
        for (int s = 0; s < 32; s++) all &= msk_s[s];
        if (all) msk_s[0] = 0;
        gscale[b] = all ? 0.0f : mask_n[b];
    }

    {
        f32x4 s0 = {0.f,0.f,0.f,0.f}, s1 = {0.f,0.f,0.f,0.f};
        int kb = w * 128;
#pragma unroll
        for (int kk = 0; kk < 4; kk++) {
            int k0 = kb + kk * 32;
            bf16x8 b0 = *(const bf16x8*)(glb + lm * 520 + k0 + quad * 8);
            bf16x8 b1 = *(const bf16x8*)(glb + (16 + lm) * 520 + k0 + quad * 8);
            s0 = __builtin_amdgcn_mfma_f32_16x16x32_bf16(af[kk], b0, s0, 0, 0, 0);
            s1 = __builtin_amdgcn_mfma_f32_16x16x32_bf16(af[kk], b1, s1, 0, 0, 0);
        }
        if (quad == 0) {
            sp[w * 64 + lm] = s0[0];
            sp[w * 64 + 32 + lm] = s0[1];
            sp[w * 64 + 16 + lm] = s1[0];
            sp[w * 64 + 48 + lm] = s1[1];
        }
    }
    __syncthreads();

    if (t < 64) {
        int s = t & 31;
        float v = sp[t] + sp[64 + t] + sp[128 + t] + sp[192 + t];
        int mk = msk_s[s];
        float vm = mk ? -1e30f : v;
        for (int off = 16; off > 0; off >>= 1) vm = fmaxf(vm, __shfl_xor(vm, off, 64));
        float ex = mk ? 0.0f : __expf(v - vm);
        float sm = ex;
        for (int off = 16; off > 0; off >>= 1) sm += __shfl_xor(sm, off, 64);
        wls[t] = ex / sm;
    }
    __syncthreads();

    if (t < 32) aw_out[(size_t)b * 32 + t] = 0.5f * (wls[t] + wls[32 + t]);

    {
        int h = t >> 7, jg = (t & 127) << 2;
        float a0 = 0.f, a1 = 0.f, a2 = 0.f, a3 = 0.f;
        const float* wrow = wls + h * 32;
        for (int s4 = 0; s4 < 8; s4++) {
            float4 wv = *(const float4*)(wrow + s4 * 4);
#pragma unroll
            for (int si = 0; si < 4; si++) {
                int s = s4 * 4 + si;
                ushort4 gv = *(const ushort4*)(glb + s * 520 + jg);
                float wq = (si == 0) ? wv.x : (si == 1) ? wv.y : (si == 2) ? wv.z : wv.w;
                a0 += wq * bf2f(gv.x); a1 += wq * bf2f(gv.y);
                a2 += wq * bf2f(gv.z); a3 += wq * bf2f(gv.w);
            }
        }
        ushort4 ov;
        ov.x = f2bf(a0); ov.y = f2bf(a1); ov.z = f2bf(a2); ov.w = f2bf(a3);
        *(ushort4*)(G + (size_t)b * 1024 + h * 512 + jg) = ov;
    }
}

extern "C" void kernel_launch(void* const* d_in, const int* in_sizes, int n_in,
                              void* d_out, int out_size, void* d_ws, size_t ws_size,
                              hipStream_t stream)
{
    const float* src   = (const float*)d_in[0];
    const float* gene  = (const float*)d_in[1];
    const void*  mask  = d_in[2];
    const float* maskn = (const float*)d_in[3];
    const float* Wq    = (const float*)d_in[4];
    const float* bq    = (const float*)d_in[5];
    const float* Wk    = (const float*)d_in[6];
    // d_in[7] = bk: cancels in softmax, unused
    const float* Wv    = (const float*)d_in[8];
    const float* bv    = (const float*)d_in[9];
    const float* Wout  = (const float*)d_in[10];
    const float* bout  = (const float*)d_in[11];

    float* out = (float*)d_out;
    float* aw  = out + (size_t)NB * DM;

    char* ws = (char*)d_ws;
    size_t off = 0;
    auto alloc = [&](size_t bytes) -> void* {
        void* p = ws + off;
        off = (off + bytes + 255) & ~((size_t)255);
        return p;
    };
    int* mode            = (int*)alloc(4);
    unsigned short* srcb = (unsigned short*)alloc((size_t)NB * DM * 2);    // 4 MiB
    unsigned short* Cb   = (unsigned short*)alloc((size_t)1024 * 512 * 2); // 1 MiB
    unsigned short* Db   = (unsigned short*)alloc((size_t)512 * 1024 * 2); // 1 MiB
    float* cb            = (float*)alloc(1024 * 4);
    float* ev            = (float*)alloc(512 * 4);
    unsigned short* QKb  = (unsigned short*)alloc((size_t)NB * 1024 * 2);  // 8 MiB
    unsigned short* G    = (unsigned short*)alloc((size_t)NB * 1024 * 2);  // 8 MiB
    float* gs            = (float*)alloc((size_t)NB * 4);

    k_prep_cd<<<519, 256, 0, stream>>>(src, Wq, bq, Wk, Wv, Wout, bv, bout,
                                       (const unsigned int*)mask,
                                       srcb, cb, ev, mode, Cb, Db);
    k_gemm_bt<0><<<(4096 / 64) * (1024 / 64), 256, 0, stream>>>(
        srcb, Cb, QKb, cb, nullptr, nullptr, 4096, 1024, 512);
    k_attn<<<NB, 256, 0, stream>>>(gene, QKb, mask, mode, maskn, G, gs, aw);
    k_gemm_bt<1><<<(4096 / 64) * (512 / 64), 256, 0, stream>>>(
        G, Db, out, ev, gs, src, 4096, 512, 1024);
}